// Round 2
// baseline (783.269 us; speedup 1.0000x reference)
//
#include <hip/hip_runtime.h>

// N_NODES=100000, N_EDGES=800000, D_EDGE=64, D_NODE=128, D_IN=256, D_OUT=128
//
// Pipeline per call:
//   memset counts (800 KB) -> hist -> scan(S1,S2,S3) -> fill perm -> gather -> gemm
// CSR build replaces 102M fp32 atomics with 3.2M int atomics on L2-resident tables.

#define NB 64  // nodes per block in the GEMM kernel

// ---------------------------------------------------------------------------
// Histogram: counts[type*N + recv] ++ over both edge types in one launch.
// ---------------------------------------------------------------------------
__global__ __launch_bounds__(256) void hist_kernel(
    const int* __restrict__ recv_a, const int* __restrict__ recv_b,
    int* __restrict__ counts, int E, int N) {
  const int i = blockIdx.x * 256 + threadIdx.x;
  if (i >= 2 * E) return;
  const int t = (i >= E);
  const int e = t ? i - E : i;
  const int r = t ? recv_b[e] : recv_a[e];
  atomicAdd(&counts[t * N + r], 1);
}

// ---------------------------------------------------------------------------
// Hierarchical exclusive scan over counts[0 .. n) -> row_start.
// S1: per-block (1024 elems) local exclusive scan + block totals
// S2: scan of block totals (single block), writes sentinel row_start[n]
// S3: add block offsets, also mirror into cursor[] for the fill phase
// ---------------------------------------------------------------------------
__global__ __launch_bounds__(256) void scan_s1(
    const int* __restrict__ counts, int* __restrict__ row_start,
    int* __restrict__ block_sums, int n) {
  __shared__ int sdata[256];
  const int t = threadIdx.x;
  const int i0 = blockIdx.x * 1024 + t * 4;
  int c0 = 0, c1 = 0, c2 = 0, c3 = 0;
  if (i0 + 3 < n) {
    const int4 v = *(const int4*)&counts[i0];
    c0 = v.x; c1 = v.y; c2 = v.z; c3 = v.w;
  } else {
    if (i0 + 0 < n) c0 = counts[i0 + 0];
    if (i0 + 1 < n) c1 = counts[i0 + 1];
    if (i0 + 2 < n) c2 = counts[i0 + 2];
    if (i0 + 3 < n) c3 = counts[i0 + 3];
  }
  const int s = c0 + c1 + c2 + c3;
  // Hillis-Steele inclusive scan over 256 per-thread sums
  sdata[t] = s;
  __syncthreads();
  int v = s;
  for (int d = 1; d < 256; d <<= 1) {
    const int add = (t >= d) ? sdata[t - d] : 0;
    __syncthreads();
    v += add;
    sdata[t] = v;
    __syncthreads();
  }
  const int excl = v - s;
  if (i0 + 0 < n) row_start[i0 + 0] = excl;
  if (i0 + 1 < n) row_start[i0 + 1] = excl + c0;
  if (i0 + 2 < n) row_start[i0 + 2] = excl + c0 + c1;
  if (i0 + 3 < n) row_start[i0 + 3] = excl + c0 + c1 + c2;
  if (t == 255) block_sums[blockIdx.x] = v;
}

__global__ __launch_bounds__(256) void scan_s2(
    int* __restrict__ block_sums, int* __restrict__ row_start,
    int nblocks, int n, int total) {
  __shared__ int sdata[256];
  const int t = threadIdx.x;
  const int s = (t < nblocks) ? block_sums[t] : 0;
  sdata[t] = s;
  __syncthreads();
  int v = s;
  for (int d = 1; d < 256; d <<= 1) {
    const int add = (t >= d) ? sdata[t - d] : 0;
    __syncthreads();
    v += add;
    sdata[t] = v;
    __syncthreads();
  }
  if (t < nblocks) block_sums[t] = v - s;  // exclusive
  if (t == 0) row_start[n] = total;        // sentinel
}

__global__ __launch_bounds__(256) void scan_s3(
    int* __restrict__ row_start, int* __restrict__ cursor,
    const int* __restrict__ block_sums, int n) {
  const int i0 = blockIdx.x * 1024 + threadIdx.x * 4;
  const int off = block_sums[blockIdx.x];
#pragma unroll
  for (int j = 0; j < 4; ++j) {
    if (i0 + j < n) {
      const int v = row_start[i0 + j] + off;
      row_start[i0 + j] = v;
      cursor[i0 + j] = v;
    }
  }
}

// ---------------------------------------------------------------------------
// Fill permutation: perm[cursor[t*N+r]++] = e
// ---------------------------------------------------------------------------
__global__ __launch_bounds__(256) void fill_kernel(
    const int* __restrict__ recv_a, const int* __restrict__ recv_b,
    int* __restrict__ cursor, int* __restrict__ perm, int E, int N) {
  const int i = blockIdx.x * 256 + threadIdx.x;
  if (i >= 2 * E) return;
  const int t = (i >= E);
  const int e = t ? i - E : i;
  const int r = t ? recv_b[e] : recv_a[e];
  const int pos = atomicAdd(&cursor[t * N + r], 1);
  perm[pos] = e;
}

// ---------------------------------------------------------------------------
// Gather: one wave per (node, type). 16 lanes x float4 cover one edge's 64
// features -> 4 edges in flight per loop iteration. Cross-group shfl reduce.
// Writes every row (zeros for deg-0 nodes) -> no big memset needed.
// ---------------------------------------------------------------------------
__global__ __launch_bounds__(256) void gather_kernel(
    const float* __restrict__ edata_a, const float* __restrict__ edata_b,
    const int* __restrict__ perm, const int* __restrict__ row_start,
    float* __restrict__ agg_a, float* __restrict__ agg_b, int N) {
  const int w = blockIdx.x * 4 + (threadIdx.x >> 6);
  if (w >= 2 * N) return;
  const int lane = threadIdx.x & 63;
  const int t = (w >= N);
  const int n = t ? w - N : w;
  const int start = row_start[w];
  const int end = row_start[w + 1];
  const float* __restrict__ ed = t ? edata_b : edata_a;
  float* __restrict__ ag = t ? agg_b : agg_a;
  const int g = lane >> 4;          // edge slot within wave (0..3)
  const int fo = (lane & 15) << 2;  // feature float4 offset

  float4 acc = {0.f, 0.f, 0.f, 0.f};
  for (int j = start + g; j < end; j += 4) {
    const int e = perm[j];
    const float4 v = *(const float4*)(ed + (size_t)e * 64 + fo);
    acc.x += v.x; acc.y += v.y; acc.z += v.z; acc.w += v.w;
  }
#pragma unroll
  for (int m = 16; m <= 32; m <<= 1) {
    acc.x += __shfl_xor(acc.x, m);
    acc.y += __shfl_xor(acc.y, m);
    acc.z += __shfl_xor(acc.z, m);
    acc.w += __shfl_xor(acc.w, m);
  }
  if (g == 0) *(float4*)(ag + (size_t)n * 64 + fo) = acc;
}

// ---------------------------------------------------------------------------
// Fused concat + GEMM + bias (NB=64 nodes per 256-thread block).
// ---------------------------------------------------------------------------
__device__ __forceinline__ void fma4(float4& acc, float s, const float4& w) {
  acc.x = fmaf(s, w.x, acc.x);
  acc.y = fmaf(s, w.y, acc.y);
  acc.z = fmaf(s, w.z, acc.z);
  acc.w = fmaf(s, w.w, acc.w);
}

__global__ __launch_bounds__(256) void fused_gemm_kernel(
    const float* __restrict__ agg_a, const float* __restrict__ agg_b,
    const float* __restrict__ vdata, const float* __restrict__ W,
    const float* __restrict__ bias, float* __restrict__ out, int n_nodes) {
  __shared__ float xs[NB][260];

  const int tid = threadIdx.x;
  const int n0 = blockIdx.x * NB;
  const int nvalid = min(NB, n_nodes - n0);

  const float4* A4 = (const float4*)(agg_a + (size_t)n0 * 64);
  const float4* B4 = (const float4*)(agg_b + (size_t)n0 * 64);
  const float4* V4 = (const float4*)(vdata + (size_t)n0 * 128);
  const int limAB = nvalid * 16, limV = nvalid * 32;
  const float4 z4 = {0.f, 0.f, 0.f, 0.f};

#pragma unroll
  for (int i = tid; i < NB * 16; i += 256) {
    const int node = i >> 4;
    const int kk = (i & 15) << 2;
    *(float4*)&xs[node][kk]      = (i < limAB) ? A4[i] : z4;
    *(float4*)&xs[node][64 + kk] = (i < limAB) ? B4[i] : z4;
  }
#pragma unroll
  for (int i = tid; i < NB * 32; i += 256) {
    const int node = i >> 5;
    const int kk = (i & 31) << 2;
    *(float4*)&xs[node][128 + kk] = (i < limV) ? V4[i] : z4;
  }
  __syncthreads();

  const int c = tid & 31;     // output float4 column (cols 4c..4c+3)
  const int nset = tid >> 5;  // node group: nodes nset*8 .. nset*8+7
  const float4* W4 = (const float4*)W;

  float4 acc[8] = {};

#pragma unroll 2
  for (int k = 0; k < 256; k += 4) {
    const float4 w0 = W4[(k + 0) * 32 + c];
    const float4 w1 = W4[(k + 1) * 32 + c];
    const float4 w2 = W4[(k + 2) * 32 + c];
    const float4 w3 = W4[(k + 3) * 32 + c];
#pragma unroll
    for (int nn = 0; nn < 8; ++nn) {
      const float4 x = *(const float4*)&xs[nset * 8 + nn][k];
      fma4(acc[nn], x.x, w0);
      fma4(acc[nn], x.y, w1);
      fma4(acc[nn], x.z, w2);
      fma4(acc[nn], x.w, w3);
    }
  }

  const float4 bb = ((const float4*)bias)[c];
  float4* O4 = (float4*)out;
#pragma unroll
  for (int nn = 0; nn < 8; ++nn) {
    const int node = n0 + nset * 8 + nn;
    if (node < n_nodes) {
      float4 r = acc[nn];
      r.x += bb.x; r.y += bb.y; r.z += bb.z; r.w += bb.w;
      O4[(size_t)node * 32 + c] = r;
    }
  }
}

// ---------------------------------------------------------------------------
// Launch
// ---------------------------------------------------------------------------
extern "C" void kernel_launch(void* const* d_in, const int* in_sizes, int n_in,
                              void* d_out, int out_size, void* d_ws, size_t ws_size,
                              hipStream_t stream) {
  const float* vdata   = (const float*)d_in[0];
  const float* edata_a = (const float*)d_in[1];
  const float* edata_b = (const float*)d_in[2];
  const int*   conn_a  = (const int*)d_in[3];  // [2, E] int32
  const int*   conn_b  = (const int*)d_in[4];
  const float* W       = (const float*)d_in[5];
  const float* bias    = (const float*)d_in[6];
  float*       out     = (float*)d_out;

  const int N = in_sizes[0] / 128;  // 100000 nodes
  const int E = in_sizes[1] / 64;   // 800000 edges

  const int* recv_a = conn_a + E;  // row 1 = receivers
  const int* recv_b = conn_b + E;

  // workspace layout
  float* agg_a     = (float*)d_ws;                          // N*64 f32
  float* agg_b     = agg_a + (size_t)N * 64;                // N*64 f32
  int*   perm      = (int*)(agg_b + (size_t)N * 64);        // 2E int
  int*   counts    = perm + 2 * (size_t)E;                  // 2N int
  int*   row_start = counts + 2 * (size_t)N;                // 2N+1 int
  int*   cursor    = row_start + 2 * (size_t)N + 1;         // 2N int
  int*   block_sums = cursor + 2 * (size_t)N;               // <=256 int

  hipMemsetAsync(counts, 0, 2 * (size_t)N * sizeof(int), stream);

  const int eblocks = (2 * E + 255) / 256;  // 6250
  hist_kernel<<<eblocks, 256, 0, stream>>>(recv_a, recv_b, counts, E, N);

  const int n2 = 2 * N;                       // 200000 scan elements
  const int sblocks = (n2 + 1023) / 1024;     // 196 (must be <= 256)
  scan_s1<<<sblocks, 256, 0, stream>>>(counts, row_start, block_sums, n2);
  scan_s2<<<1, 256, 0, stream>>>(block_sums, row_start, sblocks, n2, 2 * E);
  scan_s3<<<sblocks, 256, 0, stream>>>(row_start, cursor, block_sums, n2);

  fill_kernel<<<eblocks, 256, 0, stream>>>(recv_a, recv_b, cursor, perm, E, N);

  const int gwaves = 2 * N;                   // one wave per (node,type)
  gather_kernel<<<(gwaves + 3) / 4, 256, 0, stream>>>(
      edata_a, edata_b, perm, row_start, agg_a, agg_b, N);

  const int gblocks = (N + NB - 1) / NB;      // 1563
  fused_gemm_kernel<<<gblocks, 256, 0, stream>>>(agg_a, agg_b, vdata, W, bias, out, N);
}